// Round 3
// baseline (325.404 us; speedup 1.0000x reference)
//
#include <hip/hip_runtime.h>
#include <cstdint>

// Problem constants: B=4, S=1024, D=768, H=12, dh=64
#define BB 4
#define SS 1024
#define DD 768
#define HH 12
#define DH 64

typedef unsigned short u16;
typedef unsigned int   u32;
typedef __attribute__((ext_vector_type(8))) short bf16x8;
typedef __attribute__((ext_vector_type(4))) float f32x4;

// fp32 -> bf16 RNE (finite values)
__device__ __forceinline__ u16 f2bf(float f) {
    u32 u = __float_as_uint(f);
    u += 0x7fffu + ((u >> 16) & 1u);
    return (u16)(u >> 16);
}
__device__ __forceinline__ float b2f(u32 lo16) {
    return __uint_as_float(lo16 << 16);
}

// 2^x via v_exp_f32 (gfx950 exp is base-2)
__device__ __forceinline__ float fast_exp2(float x) {
    return __builtin_amdgcn_exp2f(x);
}

// pack two f32 -> packed bf16x2. gfx950 has V_CVT_PK_BF16_F32.
#if __has_builtin(__builtin_amdgcn_cvt_pk_bf16_f32)
__device__ __forceinline__ u32 pack2(float a, float b) {
    auto r = __builtin_amdgcn_cvt_pk_bf16_f32(a, b);
    u32 v; __builtin_memcpy(&v, &r, 4); return v;
}
#else
__device__ __forceinline__ u32 pack2(float a, float b) {
    return (u32)f2bf(a) | ((u32)f2bf(b) << 16);
}
#endif

// async global->LDS, 16 B per lane. GLOBAL pointer is PER-LANE; LDS dest is
// wave-uniform base, HW adds lane*16 (m104/m108).
#define ASYNC16(gp, lp) __builtin_amdgcn_global_load_lds( \
    (const __attribute__((address_space(1))) void*)(gp),  \
    (__attribute__((address_space(3))) void*)(lp), 16, 0, 0)

// ---------------- MFMA GEMM body (NT: A[M,K], B[N,K], both K-contiguous bf16) ----
template<int BM_, int BN_, class Epi>
__device__ __forceinline__ void mfma_gemm(
    const u16* __restrict__ A, const u16* __restrict__ B,
    int K, int lda, int ldb, int m0, int n0, const Epi& epi)
{
    constexpr int MI = BM_ / 32;
    constexpr int NJ = BN_ / 32;
    __shared__ u16 Alds[BM_ * 32];
    __shared__ u16 Blds[BN_ * 32];

    const int tid  = threadIdx.x;
    const int wave = tid >> 6;
    const int lane = tid & 63;
    const int wr = wave >> 1, wc = wave & 1;

    const int ar = lane >> 2;
    const int ac = (lane & 3) * 8;

    f32x4 acc[MI][NJ] = {};

    for (int k0 = 0; k0 < K; k0 += 32) {
        __syncthreads();
#pragma unroll
        for (int j = 0; j < BM_ / 64; ++j) {
            const int rb = wave * (BM_ / 4) + j * 16;
            ASYNC16(A + (size_t)(m0 + rb + ar) * lda + k0 + ac, &Alds[rb * 32]);
        }
#pragma unroll
        for (int j = 0; j < BN_ / 64; ++j) {
            const int rb = wave * (BN_ / 4) + j * 16;
            ASYNC16(B + (size_t)(n0 + rb + ar) * ldb + k0 + ac, &Blds[rb * 32]);
        }
        __syncthreads();

        bf16x8 af[MI], bfr[NJ];
#pragma unroll
        for (int mi = 0; mi < MI; ++mi)
            af[mi] = *(const bf16x8*)&Alds[(wr * (BM_ / 2) + mi * 16 + (lane & 15)) * 32 + (lane >> 4) * 8];
#pragma unroll
        for (int nj = 0; nj < NJ; ++nj)
            bfr[nj] = *(const bf16x8*)&Blds[(wc * (BN_ / 2) + nj * 16 + (lane & 15)) * 32 + (lane >> 4) * 8];
#pragma unroll
        for (int mi = 0; mi < MI; ++mi)
#pragma unroll
            for (int nj = 0; nj < NJ; ++nj)
                acc[mi][nj] = __builtin_amdgcn_mfma_f32_16x16x32_bf16(
                    af[mi], bfr[nj], acc[mi][nj], 0, 0, 0);
    }

#pragma unroll
    for (int mi = 0; mi < MI; ++mi)
#pragma unroll
        for (int nj = 0; nj < NJ; ++nj)
#pragma unroll
            for (int r = 0; r < 4; ++r)
                epi(m0 + wr * (BM_ / 2) + mi * 16 + (lane >> 4) * 4 + r,
                    n0 + wc * (BN_ / 2) + nj * 16 + (lane & 15),
                    acc[mi][nj][r]);
}

// padded Clds row length (u16)
#define CPAD 136

// ---------------- qkv GEMM (custom, LDS-coalesced epilogue) ----------------
__global__ __launch_bounds__(256) void qkv_gemm_kernel(
    const u16* __restrict__ xb, const u16* __restrict__ Wt,
    const float* __restrict__ bias,
    u16* __restrict__ qb, u16* __restrict__ kb, u16* __restrict__ vb)
{
    __shared__ u16 Alds[128 * 32];
    __shared__ u16 Blds[128 * 32];
    __shared__ u16 Clds[128 * CPAD];

    const int tid  = threadIdx.x;
    const int wave = tid >> 6;
    const int lane = tid & 63;
    const int wr = wave >> 1, wc = wave & 1;
    const int ar = lane >> 2;
    const int ac = (lane & 3) * 8;
    const int m0 = blockIdx.y * 128, n0 = blockIdx.x * 128;

    f32x4 acc[4][4] = {};

    for (int k0 = 0; k0 < DD; k0 += 32) {
        __syncthreads();
#pragma unroll
        for (int j = 0; j < 2; ++j) {
            const int rb = wave * 32 + j * 16;
            ASYNC16(xb + (size_t)(m0 + rb + ar) * DD + k0 + ac, &Alds[rb * 32]);
            ASYNC16(Wt + (size_t)(n0 + rb + ar) * DD + k0 + ac, &Blds[rb * 32]);
        }
        __syncthreads();

        bf16x8 af[4], bfr[4];
#pragma unroll
        for (int mi = 0; mi < 4; ++mi)
            af[mi] = *(const bf16x8*)&Alds[(wr * 64 + mi * 16 + (lane & 15)) * 32 + (lane >> 4) * 8];
#pragma unroll
        for (int nj = 0; nj < 4; ++nj)
            bfr[nj] = *(const bf16x8*)&Blds[(wc * 64 + nj * 16 + (lane & 15)) * 32 + (lane >> 4) * 8];
#pragma unroll
        for (int mi = 0; mi < 4; ++mi)
#pragma unroll
            for (int nj = 0; nj < 4; ++nj)
                acc[mi][nj] = __builtin_amdgcn_mfma_f32_16x16x32_bf16(
                    af[mi], bfr[nj], acc[mi][nj], 0, 0, 0);
    }

    const int c  = n0 / DD;
    const int w0 = n0 - c * DD;
    const int hA = w0 >> 6;
    const float qs = (c == 0) ? 0.125f : 1.0f;
#pragma unroll
    for (int mi = 0; mi < 4; ++mi)
#pragma unroll
        for (int nj = 0; nj < 4; ++nj)
#pragma unroll
            for (int r = 0; r < 4; ++r) {
                const int row = wr * 64 + mi * 16 + (lane >> 4) * 4 + r;
                const int col = wc * 64 + nj * 16 + (lane & 15);
                Clds[row * CPAD + col] = f2bf((acc[mi][nj][r] + bias[n0 + col]) * qs);
            }
    __syncthreads();

    u16* const dst = (c == 0) ? qb : (c == 1) ? kb : vb;
    const int b = m0 >> 10;
#pragma unroll
    for (int j = 0; j < 8; ++j) {
        const int idx = j * 256 + tid;
        const int row = idx >> 4, u4 = idx & 15;
        const int half = u4 >> 3, d8 = u4 & 7;
        const int h = hA + half;
        const int s = (m0 + row) & 1023;
        const uint4 v = *(const uint4*)&Clds[row * CPAD + half * 64 + d8 * 8];
        *(uint4*)&dst[(((size_t)(b * HH + h) << 10) + s) * DH + d8 * 8] = v;
    }
}

// ---------------- vb -> vt transpose (per bh: 1024x64 -> 64x1024) ----------
__global__ __launch_bounds__(256) void vtrans_kernel(
    const u16* __restrict__ vb, u16* __restrict__ vt)
{
    __shared__ u16 t[64 * 72];
    const int tid = threadIdx.x;
    const int bh = blockIdx.y;
    const int s0 = blockIdx.x * 64;
    const u16* src = vb + ((size_t)bh << 16) + (size_t)s0 * DH;

#pragma unroll
    for (int j = 0; j < 2; ++j) {
        const int idx = j * 256 + tid;
        const int row = idx >> 3, u4 = idx & 7;
        *(uint4*)&t[row * 72 + u4 * 8] = *(const uint4*)&src[row * DH + u4 * 8];
    }
    __syncthreads();

#pragma unroll
    for (int j = 0; j < 2; ++j) {
        const int idx = j * 256 + tid;
        const int d = idx >> 3, u4 = idx & 7;
        u16 tmp[8];
#pragma unroll
        for (int i = 0; i < 8; ++i) tmp[i] = t[(u4 * 8 + i) * 72 + d];
        *(uint4*)&vt[((size_t)bh * DH + d) * SS + s0 + u4 * 8] = *(const uint4*)tmp;
    }
}

// ---------------- fused QK^T + mix1 + exp + denominator ---------------------
// Block = (k-range kr of 256 cols, 16 q-rows, local batch bL). 4 waves; wave w
// owns k-columns [kr*256 + kit*64 + w*16, +16) per k-iter. All 12 heads' QK
// logits computed per wave via MFMA with DIRECT global A/B fragment loads
// (L2-resident; no LDS, no barriers). All 12 h share one (q,k)->lane map, so
// mix1 is a per-lane in-register 12x12 matvec (f32) -- no transpose anywhere.
// P = exp2((mix1+bl)*log2e) stored unnormalized bf16 at P[q][k][h16] (pad
// slots 12..15 never written; consumer's A-side zeros kill them). Per-(kr,wave)
// denominator partials -> den_part[(kr*4+w)][bL][q][12] (no atomics).
__global__ __launch_bounds__(256) void qkmix_kernel(
    const u16* __restrict__ qb, const u16* __restrict__ kb,
    const float* __restrict__ Wl, const float* __restrict__ bl,
    u16* __restrict__ Pbuf, float* __restrict__ den_part, int bh0)
{
    const int tid  = threadIdx.x;
    const int wave = tid >> 6;
    const int lane = tid & 63;
    const int u    = lane >> 4;
    const int ln   = lane & 15;
    const int kr = blockIdx.x;            // 0..3
    const int q0 = blockIdx.y * 16;
    const int bL = blockIdx.z;

    f32x4 dacc[HH] = {};                  // den partial; [g], component r <-> q-row u*4+r

    for (int kit = 0; kit < 4; ++kit) {
        const int kc = kr * 256 + kit * 64 + wave * 16;
        f32x4 acc[HH] = {};
#pragma unroll
        for (int h = 0; h < HH; ++h) {
            const size_t hp = (size_t)(bh0 + bL * HH + h) << 16;  // SS*DH plane
#pragma unroll
            for (int ks = 0; ks < 2; ++ks) {
                const bf16x8 a = *(const bf16x8*)&qb[hp + (size_t)(q0 + ln) * DH + ks * 32 + u * 8];
                const bf16x8 b = *(const bf16x8*)&kb[hp + (size_t)(kc + ln) * DH + ks * 32 + u * 8];
                acc[h] = __builtin_amdgcn_mfma_f32_16x16x32_bf16(a, b, acc[h], 0, 0, 0);
            }
        }
        // D-frag: row(q) = u*4+r, col(k) = ln. mix1 + exp per slot r.
#pragma unroll
        for (int r = 0; r < 4; ++r) {
            float m[HH];
#pragma unroll
            for (int g = 0; g < HH; ++g) {
                float s = bl[g];
#pragma unroll
                for (int h = 0; h < HH; ++h) s += acc[h][r] * Wl[h * HH + g];
                m[g] = fast_exp2(s * 1.44269504f);
                dacc[g][r] += m[g];
            }
            u16* dst = Pbuf + ((size_t)(bL * SS + q0 + u * 4 + r) * SS + kc + ln) * 16;
            uint4 pa; uint2 pb;
            pa.x = pack2(m[0], m[1]);  pa.y = pack2(m[2], m[3]);
            pa.z = pack2(m[4], m[5]);  pa.w = pack2(m[6], m[7]);
            pb.x = pack2(m[8], m[9]);  pb.y = pack2(m[10], m[11]);
            *(uint4*)dst = pa;
            *(uint2*)(dst + 8) = pb;
        }
    }

    // reduce den partials over the 16 k-lanes of this wave
#pragma unroll
    for (int off = 1; off < 16; off <<= 1)
#pragma unroll
        for (int g = 0; g < HH; ++g) {
            dacc[g][0] += __shfl_xor(dacc[g][0], off);
            dacc[g][1] += __shfl_xor(dacc[g][1], off);
            dacc[g][2] += __shfl_xor(dacc[g][2], off);
            dacc[g][3] += __shfl_xor(dacc[g][3], off);
        }
    if (ln == 0) {
        const size_t dbase = ((size_t)(kr * 4 + wave) * gridDim.z + bL) * (SS * 16);
#pragma unroll
        for (int r = 0; r < 4; ++r) {
            float* dp = den_part + dbase + (size_t)(q0 + u * 4 + r) * 16;
            float4 v0, v1, v2;
            v0.x = dacc[0][r]; v0.y = dacc[1][r]; v0.z = dacc[2][r];  v0.w = dacc[3][r];
            v1.x = dacc[4][r]; v1.y = dacc[5][r]; v1.z = dacc[6][r];  v1.w = dacc[7][r];
            v2.x = dacc[8][r]; v2.y = dacc[9][r]; v2.z = dacc[10][r]; v2.w = dacc[11][r];
            *(float4*)dp = v0; *(float4*)(dp + 4) = v1; *(float4*)(dp + 8) = v2;
        }
    }
}

// ---------------- mix2: attn2[g][q][k] = Ww^T/den . P + bw -------------------
// Block = (bL, q). B-frag per lane = one coalesced 16B global load from the
// h-fast P row (h = contraction axis, lane-contiguous by construction).
// A2[g][h] = Ww[h][g]/den[h] built once; D-frag rows (g) store straight into
// the per-head attn2 planes pv consumes (16x2B contiguous chunks per group).
__global__ __launch_bounds__(256) void mix2_kernel(
    const u16* __restrict__ Pbuf, const float* __restrict__ den_part,
    const float* __restrict__ Ww, const float* __restrict__ bw,
    u16* __restrict__ attn2, int nbz)
{
    __shared__ float denS[16];
    const int tid  = threadIdx.x;
    const int wave = tid >> 6;
    const int lane = tid & 63;
    const int u    = lane >> 4;
    const int ln   = lane & 15;
    const int bL = blockIdx.x >> 10;
    const int q  = blockIdx.x & (SS - 1);

    if (tid < 16) {
        float s = 0.f;
#pragma unroll
        for (int p = 0; p < 16; ++p)
            s += den_part[((size_t)p * nbz + bL) * (SS * 16) + q * 16 + tid];
        denS[tid] = 1.0f / s;
    }
    __syncthreads();

    bf16x8 a2;
    {
        u16 t[8];
#pragma unroll
        for (int j = 0; j < 8; ++j) {
            const int h = u * 8 + j;
            t[j] = (h < HH && ln < HH) ? f2bf(Ww[h * HH + ln] * denS[h]) : (u16)0;
        }
        __builtin_memcpy(&a2, t, 16);
    }
    f32x4 c2 = {0.f, 0.f, 0.f, 0.f};
#pragma unroll
    for (int r = 0; r < 4; ++r) {
        const int g = u * 4 + r;
        c2[r] = (g < HH) ? bw[g] : 0.f;
    }

    const u16* prow = Pbuf + (size_t)(bL * SS + q) * SS * 16;
    u16* const arow = attn2 + ((size_t)(bL * HH) << 20) + ((size_t)q << 10);
#pragma unroll
    for (int mi = 0; mi < 16; ++mi) {
        const int pos = wave * 256 + mi * 16 + ln;
        const bf16x8 bf = *(const bf16x8*)&prow[(size_t)pos * 16 + (u & 1) * 8];
        const f32x4 d = __builtin_amdgcn_mfma_f32_16x16x32_bf16(a2, bf, c2, 0, 0, 0);
#pragma unroll
        for (int r = 0; r < 4; ++r) {
            const int g = u * 4 + r;
            if (g < HH)
                arow[((size_t)g << 20) + pos] = f2bf(d[r]);
        }
    }
}

// ---------------- pv (64x64 tile) ------------------------------------------
__global__ __launch_bounds__(256) void pv_gemm_kernel(
    const u16* __restrict__ attn2, const u16* __restrict__ vt,
    u16* __restrict__ ctx, int bh0)
{
    const int bhL = blockIdx.z;
    const int bh = bh0 + bhL;
    const int b = bh / HH, h = bh % HH;
    const u16* A = attn2 + (size_t)bhL * SS * SS;
    const u16* B = vt + (size_t)bh * DH * SS;
    u16* C = ctx + (size_t)b * SS * DD + h * DH;
    struct Epi {
        u16* C;
        __device__ void operator()(int m, int n, float v) const {
            C[(size_t)m * DD + n] = f2bf(v);
        }
    } epi{C};
    mfma_gemm<64, 64>(A, B, SS, SS, SS, blockIdx.y * 64, 0, epi);
}

// ---------------- proj (template) ------------------------------------------
__global__ __launch_bounds__(256) void proj_gemm_kernel(
    const u16* __restrict__ ctx, const u16* __restrict__ Wt,
    const float* __restrict__ bias, float* __restrict__ out)
{
    struct Epi {
        float* out; const float* bias;
        __device__ void operator()(int m, int n, float v) const {
            out[(size_t)m * DD + n] = v + bias[n];
        }
    } epi{out, bias};
    mfma_gemm<128, 64>(ctx, Wt, DD, DD, DD, blockIdx.y * 128, blockIdx.x * 64, epi);
}

// ---------------- conversion kernels ----------------

__global__ __launch_bounds__(256) void cvt_bf16_kernel(
    const float* __restrict__ in, u16* __restrict__ out, int n8)
{
    const int i = blockIdx.x * 256 + threadIdx.x;
    if (i >= n8) return;
    const float4 a = ((const float4*)in)[i * 2];
    const float4 b = ((const float4*)in)[i * 2 + 1];
    uint4 p;
    p.x = pack2(a.x, a.y); p.y = pack2(a.z, a.w);
    p.z = pack2(b.x, b.y); p.w = pack2(b.z, b.w);
    ((uint4*)out)[i] = p;
}

__global__ __launch_bounds__(256) void cvt_transpose_kernel(
    const float* __restrict__ in, u16* __restrict__ out, int R, int C)
{
    __shared__ float t[32][33];
    const int c0 = blockIdx.x * 32, r0 = blockIdx.y * 32;
    const int tr = threadIdx.x >> 3;
    const int tc = (threadIdx.x & 7) * 4;
    const float4 v = *(const float4*)&in[(size_t)(r0 + tr) * C + c0 + tc];
    t[tc + 0][tr] = v.x; t[tc + 1][tr] = v.y;
    t[tc + 2][tr] = v.z; t[tc + 3][tr] = v.w;
    __syncthreads();
    uint2 p;
    p.x = pack2(t[tr][tc + 0], t[tr][tc + 1]);
    p.y = pack2(t[tr][tc + 2], t[tr][tc + 3]);
    *(uint2*)&out[(size_t)(c0 + tr) * R + r0 + tc] = p;
}

// ---------------- launch ----------------
extern "C" void kernel_launch(void* const* d_in, const int* in_sizes, int n_in,
                              void* d_out, int out_size, void* d_ws, size_t ws_size,
                              hipStream_t stream)
{
    const float* x     = (const float*)d_in[0];
    const float* Wqkv  = (const float*)d_in[1];
    const float* bqkv  = (const float*)d_in[2];
    const float* Wl    = (const float*)d_in[3];
    const float* bl    = (const float*)d_in[4];
    const float* Ww    = (const float*)d_in[5];
    const float* bw    = (const float*)d_in[6];
    const float* Wproj = (const float*)d_in[7];
    const float* bproj = (const float*)d_in[8];
    float* out = (float*)d_out;

    // workspace (bf16 elems unless noted)
    const size_t N_XB  = (size_t)BB * SS * DD;
    const size_t N_QB  = (size_t)BB * HH * SS * DH;
    const size_t N_WT  = (size_t)DD * 3 * DD;
    const size_t N_WP  = (size_t)DD * DD;
    const size_t N_AT1 = (size_t)HH * SS * SS;          // attn2 per batch
    const size_t N_P   = (size_t)SS * SS * 16;          // P per batch
    const size_t N_DEN = (size_t)16 * SS * 16;          // den_part f32 per batch

    u16* xb  = (u16*)d_ws;
    u16* qb  = xb  + N_XB;
    u16* kb  = qb  + N_QB;
    u16* vb  = kb  + N_QB;
    u16* vt  = vb  + N_QB;
    u16* ctx = vt  + N_QB;
    u16* Wqkv_t = ctx + N_XB;
    u16* Wproj_t = Wqkv_t + N_WT;

    const size_t fixed_bytes = (size_t)(N_XB * 2 + N_QB * 4 + N_WT + N_WP) * 2;
    int b_per = BB;
    while (b_per > 1 &&
           fixed_bytes + (size_t)b_per * ((N_P + N_AT1) * 2 + N_DEN * 4) > ws_size)
        b_per >>= 1;
    const int n_iter = BB / b_per;

    u16* Pbuf  = Wproj_t + N_WP;
    u16* attn2 = Pbuf + (size_t)b_per * N_P;
    float* den_part = (float*)(attn2 + (size_t)b_per * N_AT1);

    const dim3 blk(256);

    // 0) conversions
    cvt_bf16_kernel<<<dim3((N_XB / 8 + 255) / 256), blk, 0, stream>>>(x, xb, (int)(N_XB / 8));
    cvt_transpose_kernel<<<dim3(3 * DD / 32, DD / 32), blk, 0, stream>>>(Wqkv, Wqkv_t, DD, 3 * DD);
    cvt_transpose_kernel<<<dim3(DD / 32, DD / 32), blk, 0, stream>>>(Wproj, Wproj_t, DD, DD);

    // 1) QKV projection (qb scaled, kb, vb) + v transpose
    qkv_gemm_kernel<<<dim3(3 * DD / 128, BB * SS / 128), blk, 0, stream>>>(
        xb, Wqkv_t, bqkv, qb, kb, vb);
    vtrans_kernel<<<dim3(SS / 64, BB * HH), blk, 0, stream>>>(vb, vt);

    for (int it = 0; it < n_iter; ++it) {
        const int bh0 = it * b_per * HH;
        // 2) QK^T + mix1 + exp + denominator partials
        qkmix_kernel<<<dim3(4, SS / 16, b_per), blk, 0, stream>>>(
            qb, kb, Wl, bl, Pbuf, den_part, bh0);
        // 3) mix2 (normalize + post-softmax head mix) -> attn2 planes
        mix2_kernel<<<dim3(b_per * SS), blk, 0, stream>>>(
            Pbuf, den_part, Ww, bw, attn2, b_per);
        // 4) PV (64x64 tiles)
        pv_gemm_kernel<<<dim3(1, SS / 64, b_per * HH), blk, 0, stream>>>(
            attn2, vt, ctx, bh0);
    }

    // 5) output projection
    proj_gemm_kernel<<<dim3(DD / 64, BB * SS / 128), blk, 0, stream>>>(
        ctx, Wproj_t, bproj, out);
}

// Round 4
// 248.189 us; speedup vs baseline: 1.3111x; 1.3111x over previous
//
#include <hip/hip_runtime.h>
#include <cstdint>

// Problem constants: B=4, S=1024, D=768, H=12, dh=64
#define BB 4
#define SS 1024
#define DD 768
#define HH 12
#define DH 64

typedef unsigned short u16;
typedef unsigned int   u32;
typedef __attribute__((ext_vector_type(8))) short bf16x8;
typedef __attribute__((ext_vector_type(4))) float f32x4;

// fp32 -> bf16 RNE (finite values)
__device__ __forceinline__ u16 f2bf(float f) {
    u32 u = __float_as_uint(f);
    u += 0x7fffu + ((u >> 16) & 1u);
    return (u16)(u >> 16);
}
__device__ __forceinline__ float b2f(u32 lo16) {
    return __uint_as_float(lo16 << 16);
}

// 2^x via v_exp_f32 (gfx950 exp is base-2)
__device__ __forceinline__ float fast_exp2(float x) {
    return __builtin_amdgcn_exp2f(x);
}

// pack two f32 -> packed bf16x2. gfx950 has V_CVT_PK_BF16_F32.
#if __has_builtin(__builtin_amdgcn_cvt_pk_bf16_f32)
__device__ __forceinline__ u32 pack2(float a, float b) {
    auto r = __builtin_amdgcn_cvt_pk_bf16_f32(a, b);
    u32 v; __builtin_memcpy(&v, &r, 4); return v;
}
#else
__device__ __forceinline__ u32 pack2(float a, float b) {
    return (u32)f2bf(a) | ((u32)f2bf(b) << 16);
}
#endif

// async global->LDS, 16 B per lane. GLOBAL pointer is PER-LANE; LDS dest is
// wave-uniform base, HW adds lane*16 (m104/m108).
#define ASYNC16(gp, lp) __builtin_amdgcn_global_load_lds( \
    (const __attribute__((address_space(1))) void*)(gp),  \
    (__attribute__((address_space(3))) void*)(lp), 16, 0, 0)

// ---------------- MFMA GEMM body (NT: A[M,K], B[N,K], both K-contiguous bf16) ----
template<int BM_, int BN_, class Epi>
__device__ __forceinline__ void mfma_gemm(
    const u16* __restrict__ A, const u16* __restrict__ B,
    int K, int lda, int ldb, int m0, int n0, const Epi& epi)
{
    constexpr int MI = BM_ / 32;
    constexpr int NJ = BN_ / 32;
    __shared__ u16 Alds[BM_ * 32];
    __shared__ u16 Blds[BN_ * 32];

    const int tid  = threadIdx.x;
    const int wave = tid >> 6;
    const int lane = tid & 63;
    const int wr = wave >> 1, wc = wave & 1;

    const int ar = lane >> 2;
    const int ac = (lane & 3) * 8;

    f32x4 acc[MI][NJ] = {};

    for (int k0 = 0; k0 < K; k0 += 32) {
        __syncthreads();
#pragma unroll
        for (int j = 0; j < BM_ / 64; ++j) {
            const int rb = wave * (BM_ / 4) + j * 16;
            ASYNC16(A + (size_t)(m0 + rb + ar) * lda + k0 + ac, &Alds[rb * 32]);
        }
#pragma unroll
        for (int j = 0; j < BN_ / 64; ++j) {
            const int rb = wave * (BN_ / 4) + j * 16;
            ASYNC16(B + (size_t)(n0 + rb + ar) * ldb + k0 + ac, &Blds[rb * 32]);
        }
        __syncthreads();

        bf16x8 af[MI], bfr[NJ];
#pragma unroll
        for (int mi = 0; mi < MI; ++mi)
            af[mi] = *(const bf16x8*)&Alds[(wr * (BM_ / 2) + mi * 16 + (lane & 15)) * 32 + (lane >> 4) * 8];
#pragma unroll
        for (int nj = 0; nj < NJ; ++nj)
            bfr[nj] = *(const bf16x8*)&Blds[(wc * (BN_ / 2) + nj * 16 + (lane & 15)) * 32 + (lane >> 4) * 8];
#pragma unroll
        for (int mi = 0; mi < MI; ++mi)
#pragma unroll
            for (int nj = 0; nj < NJ; ++nj)
                acc[mi][nj] = __builtin_amdgcn_mfma_f32_16x16x32_bf16(
                    af[mi], bfr[nj], acc[mi][nj], 0, 0, 0);
    }

#pragma unroll
    for (int mi = 0; mi < MI; ++mi)
#pragma unroll
        for (int nj = 0; nj < NJ; ++nj)
#pragma unroll
            for (int r = 0; r < 4; ++r)
                epi(m0 + wr * (BM_ / 2) + mi * 16 + (lane >> 4) * 4 + r,
                    n0 + wc * (BN_ / 2) + nj * 16 + (lane & 15),
                    acc[mi][nj][r]);
}

// padded Clds row length (u16)
#define CPAD 136

// ---------------- qkv GEMM (custom, LDS-coalesced epilogue) ----------------
__global__ __launch_bounds__(256) void qkv_gemm_kernel(
    const u16* __restrict__ xb, const u16* __restrict__ Wt,
    const float* __restrict__ bias,
    u16* __restrict__ qb, u16* __restrict__ kb, u16* __restrict__ vb)
{
    __shared__ u16 Alds[128 * 32];
    __shared__ u16 Blds[128 * 32];
    __shared__ u16 Clds[128 * CPAD];

    const int tid  = threadIdx.x;
    const int wave = tid >> 6;
    const int lane = tid & 63;
    const int wr = wave >> 1, wc = wave & 1;
    const int ar = lane >> 2;
    const int ac = (lane & 3) * 8;
    const int m0 = blockIdx.y * 128, n0 = blockIdx.x * 128;

    f32x4 acc[4][4] = {};

    for (int k0 = 0; k0 < DD; k0 += 32) {
        __syncthreads();
#pragma unroll
        for (int j = 0; j < 2; ++j) {
            const int rb = wave * 32 + j * 16;
            ASYNC16(xb + (size_t)(m0 + rb + ar) * DD + k0 + ac, &Alds[rb * 32]);
            ASYNC16(Wt + (size_t)(n0 + rb + ar) * DD + k0 + ac, &Blds[rb * 32]);
        }
        __syncthreads();

        bf16x8 af[4], bfr[4];
#pragma unroll
        for (int mi = 0; mi < 4; ++mi)
            af[mi] = *(const bf16x8*)&Alds[(wr * 64 + mi * 16 + (lane & 15)) * 32 + (lane >> 4) * 8];
#pragma unroll
        for (int nj = 0; nj < 4; ++nj)
            bfr[nj] = *(const bf16x8*)&Blds[(wc * 64 + nj * 16 + (lane & 15)) * 32 + (lane >> 4) * 8];
#pragma unroll
        for (int mi = 0; mi < 4; ++mi)
#pragma unroll
            for (int nj = 0; nj < 4; ++nj)
                acc[mi][nj] = __builtin_amdgcn_mfma_f32_16x16x32_bf16(
                    af[mi], bfr[nj], acc[mi][nj], 0, 0, 0);
    }

    const int c  = n0 / DD;
    const int w0 = n0 - c * DD;
    const int hA = w0 >> 6;
    const float qs = (c == 0) ? 0.125f : 1.0f;
#pragma unroll
    for (int mi = 0; mi < 4; ++mi)
#pragma unroll
        for (int nj = 0; nj < 4; ++nj)
#pragma unroll
            for (int r = 0; r < 4; ++r) {
                const int row = wr * 64 + mi * 16 + (lane >> 4) * 4 + r;
                const int col = wc * 64 + nj * 16 + (lane & 15);
                Clds[row * CPAD + col] = f2bf((acc[mi][nj][r] + bias[n0 + col]) * qs);
            }
    __syncthreads();

    u16* const dst = (c == 0) ? qb : (c == 1) ? kb : vb;
    const int b = m0 >> 10;
#pragma unroll
    for (int j = 0; j < 8; ++j) {
        const int idx = j * 256 + tid;
        const int row = idx >> 4, u4 = idx & 15;
        const int half = u4 >> 3, d8 = u4 & 7;
        const int h = hA + half;
        const int s = (m0 + row) & 1023;
        const uint4 v = *(const uint4*)&Clds[row * CPAD + half * 64 + d8 * 8];
        *(uint4*)&dst[(((size_t)(b * HH + h) << 10) + s) * DH + d8 * 8] = v;
    }
}

// ---------------- vb -> vt transpose (per bh: 1024x64 -> 64x1024) ----------
__global__ __launch_bounds__(256) void vtrans_kernel(
    const u16* __restrict__ vb, u16* __restrict__ vt)
{
    __shared__ u16 t[64 * 72];
    const int tid = threadIdx.x;
    const int bh = blockIdx.y;
    const int s0 = blockIdx.x * 64;
    const u16* src = vb + ((size_t)bh << 16) + (size_t)s0 * DH;

#pragma unroll
    for (int j = 0; j < 2; ++j) {
        const int idx = j * 256 + tid;
        const int row = idx >> 3, u4 = idx & 7;
        *(uint4*)&t[row * 72 + u4 * 8] = *(const uint4*)&src[row * DH + u4 * 8];
    }
    __syncthreads();

#pragma unroll
    for (int j = 0; j < 2; ++j) {
        const int idx = j * 256 + tid;
        const int d = idx >> 3, u4 = idx & 7;
        u16 tmp[8];
#pragma unroll
        for (int i = 0; i < 8; ++i) tmp[i] = t[(u4 * 8 + i) * 72 + d];
        *(uint4*)&vt[((size_t)bh * DH + d) * SS + s0 + u4 * 8] = *(const uint4*)tmp;
    }
}

// ---------------- qk GEMM (custom, LDS-coalesced epilogue) -----------------
__global__ __launch_bounds__(256) void qk_gemm_kernel(
    const u16* __restrict__ qb, const u16* __restrict__ kb,
    u16* __restrict__ attn, int bh0)
{
    __shared__ u16 Alds[128 * 32];
    __shared__ u16 Blds[128 * 32];
    __shared__ u16 Clds[128 * CPAD];

    const int tid  = threadIdx.x;
    const int wave = tid >> 6;
    const int lane = tid & 63;
    const int wr = wave >> 1, wc = wave & 1;
    const int ar = lane >> 2;
    const int ac = (lane & 3) * 8;
    const int m0 = blockIdx.y * 128, n0 = blockIdx.x * 128;

    const int bhL = blockIdx.z;
    const u16* A = qb + (size_t)(bh0 + bhL) * SS * DH;
    const u16* B = kb + (size_t)(bh0 + bhL) * SS * DH;
    u16* C = attn + (size_t)bhL * SS * SS;

    f32x4 acc[4][4] = {};

#pragma unroll
    for (int k0 = 0; k0 < DH; k0 += 32) {
        __syncthreads();
#pragma unroll
        for (int j = 0; j < 2; ++j) {
            const int rb = wave * 32 + j * 16;
            ASYNC16(A + (size_t)(m0 + rb + ar) * DH + k0 + ac, &Alds[rb * 32]);
            ASYNC16(B + (size_t)(n0 + rb + ar) * DH + k0 + ac, &Blds[rb * 32]);
        }
        __syncthreads();

        bf16x8 af[4], bfr[4];
#pragma unroll
        for (int mi = 0; mi < 4; ++mi)
            af[mi] = *(const bf16x8*)&Alds[(wr * 64 + mi * 16 + (lane & 15)) * 32 + (lane >> 4) * 8];
#pragma unroll
        for (int nj = 0; nj < 4; ++nj)
            bfr[nj] = *(const bf16x8*)&Blds[(wc * 64 + nj * 16 + (lane & 15)) * 32 + (lane >> 4) * 8];
#pragma unroll
        for (int mi = 0; mi < 4; ++mi)
#pragma unroll
            for (int nj = 0; nj < 4; ++nj)
                acc[mi][nj] = __builtin_amdgcn_mfma_f32_16x16x32_bf16(
                    af[mi], bfr[nj], acc[mi][nj], 0, 0, 0);
    }

#pragma unroll
    for (int mi = 0; mi < 4; ++mi)
#pragma unroll
        for (int nj = 0; nj < 4; ++nj)
#pragma unroll
            for (int r = 0; r < 4; ++r) {
                const int row = wr * 64 + mi * 16 + (lane >> 4) * 4 + r;
                const int col = wc * 64 + nj * 16 + (lane & 15);
                Clds[row * CPAD + col] = f2bf(acc[mi][nj][r]);
            }
    __syncthreads();

#pragma unroll
    for (int j = 0; j < 8; ++j) {
        const int idx = j * 256 + tid;
        const int row = idx >> 4, u4 = idx & 15;
        *(uint4*)&C[(size_t)(m0 + row) * SS + n0 + u4 * 8] =
            *(const uint4*)&Clds[row * CPAD + u4 * 8];
    }
}

// ---------------- pv (64x64 tile) ------------------------------------------
__global__ __launch_bounds__(256) void pv_gemm_kernel(
    const u16* __restrict__ attn2, const u16* __restrict__ vt,
    u16* __restrict__ ctx, int bh0)
{
    const int bhL = blockIdx.z;
    const int bh = bh0 + bhL;
    const int b = bh / HH, h = bh % HH;
    const u16* A = attn2 + (size_t)bhL * SS * SS;
    const u16* B = vt + (size_t)bh * DH * SS;
    u16* C = ctx + (size_t)b * SS * DD + h * DH;
    struct Epi {
        u16* C;
        __device__ void operator()(int m, int n, float v) const {
            C[(size_t)m * DD + n] = f2bf(v);
        }
    } epi{C};
    mfma_gemm<64, 64>(A, B, SS, SS, SS, blockIdx.y * 64, 0, epi);
}

// ---------------- proj (template) ------------------------------------------
__global__ __launch_bounds__(256) void proj_gemm_kernel(
    const u16* __restrict__ ctx, const u16* __restrict__ Wt,
    const float* __restrict__ bias, float* __restrict__ out)
{
    struct Epi {
        float* out; const float* bias;
        __device__ void operator()(int m, int n, float v) const {
            out[(size_t)m * DD + n] = v + bias[n];
        }
    } epi{out, bias};
    mfma_gemm<128, 64>(ctx, Wt, DD, DD, DD, blockIdx.y * 128, blockIdx.x * 64, epi);
}

// ---------------- mix + softmax (MFMA, [pos][h16] LDS layout) ---------------
// LDS buffer is [k-pos 1024][row of 24 u16] (48 B stride, 16B-aligned rows).
// Row holds h0..h11 logits + zeros at 12..15 (cols 16..23 = never-read pad).
//  * stage-in: 12 uint2 global loads -> in-register 12x4->4x12 transpose via
//    v_perm_b32 -> 2 ds_write_b128 per row (4 rows/thread).
//  * mix1 B-frag = ONE ds_read_b128 (row pos, 16B at (u&1)*16); A1 = Wl^T
//    *log2e bf16, bias in C. exp2 on D, written back IN PLACE as ds_write_b64
//    (same wave owns the rows -> no barrier needed for P data).
//  * mix2 B-frag = ONE ds_read_b128 of P rows; A2 = Ww^T * invden; output
//    written in place (b64), then stream-out does the reverse register
//    transpose to the 12 [h][q][k] global planes.
// u>=2 lane groups read the (u&1) 16B region (finite); A-side zeros (k>=12)
// nullify their contribution -- no NaN-from-garbage hazard.
// Bank math (48B stride): fragment reads/writes start banks cycle
// {0,12,24,4,16,28,8,20} -> 2-way = free; stage-in/out (rows 4*tid) ~4-8 way
// on 16 of ~64 LDS ops -- accepted.
#define ROWB 24

__global__ __launch_bounds__(256) void mix_softmax_kernel(
    const u16* __restrict__ attn, u16* __restrict__ attn2,
    const float* __restrict__ Wl, const float* __restrict__ bl,
    const float* __restrict__ Ww, const float* __restrict__ bw)
{
    __shared__ u16 buf[SS * ROWB];         // 48 KB
    __shared__ float wsum[4][16];
    __shared__ float invd[16];

    const int tid  = threadIdx.x;
    const int wave = tid >> 6;
    const int lane = tid & 63;
    const int u    = lane >> 4;            // 16-lane group within wave
    const int ln   = lane & 15;
    const int bL = blockIdx.x >> 10;
    const int qi = blockIdx.x & (SS - 1);
    const size_t gbase = ((size_t)bL * HH * SS + qi) * SS + tid * 4;
    const int kc = tid * 4;

    // ---- stage-in: 12 uint2 loads, register transpose, vector LDS writes
    {
        uint2 src[HH];
#pragma unroll
        for (int h = 0; h < HH; ++h)
            src[h] = *(const uint2*)&attn[gbase + (size_t)h * SS * SS];

#pragma unroll
        for (int i = 0; i < 4; ++i) {
            const u32 sel = (i & 1) ? 0x07060302u : 0x05040100u;
            u32 w[6];
#pragma unroll
            for (int j = 0; j < 6; ++j) {
                const u32 lo = (i < 2) ? src[2 * j].x     : src[2 * j].y;
                const u32 hi = (i < 2) ? src[2 * j + 1].x : src[2 * j + 1].y;
                w[j] = __builtin_amdgcn_perm(hi, lo, sel);
            }
            uint4 q0; q0.x = w[0]; q0.y = w[1]; q0.z = w[2]; q0.w = w[3];
            uint4 q1; q1.x = w[4]; q1.y = w[5]; q1.z = 0u;   q1.w = 0u;
            *(uint4*)&buf[(kc + i) * ROWB + 0] = q0;
            *(uint4*)&buf[(kc + i) * ROWB + 8] = q1;
        }
    }

    // A1 frag: A[m=g][k=h] = Wl[h][g] * log2e, zero-padded
    bf16x8 a1;
    {
        u16 t[8];
#pragma unroll
        for (int j = 0; j < 8; ++j) {
            const int k = u * 8 + j;
            t[j] = (k < HH && ln < HH) ? f2bf(Wl[k * HH + ln] * 1.44269504f) : (u16)0;
        }
        __builtin_memcpy(&a1, t, 16);
    }
    f32x4 c1 = {0.f, 0.f, 0.f, 0.f};
#pragma unroll
    for (int r = 0; r < 4; ++r) {
        const int g = u * 4 + r;
        c1[r] = (g < HH) ? bl[g] * 1.44269504f : 0.f;
    }

    __syncthreads();

    const int posbase = wave * 256;
    const int fragoff = (u & 1) * 8;       // u>=2 read the finite (u&1) region

    // ---- mix1 + exp; P-exp written back in place (same-wave rows)
    float part[4] = {0.f, 0.f, 0.f, 0.f};
#pragma unroll
    for (int mi = 0; mi < 16; ++mi) {
        const int pos = posbase + mi * 16 + ln;
        const bf16x8 bfrag = *(const bf16x8*)&buf[pos * ROWB + fragoff];
        const f32x4 d = __builtin_amdgcn_mfma_f32_16x16x32_bf16(a1, bfrag, c1, 0, 0, 0);
        const float e0 = fast_exp2(d[0]);
        const float e1 = fast_exp2(d[1]);
        const float e2 = fast_exp2(d[2]);
        const float e3 = fast_exp2(d[3]);
        part[0] += e0; part[1] += e1; part[2] += e2; part[3] += e3;
        if (u < 3) {
            uint2 p;
            p.x = pack2(e0, e1); p.y = pack2(e2, e3);
            *(uint2*)&buf[pos * ROWB + u * 4] = p;
        }
    }

    // row-sum reduce: 16-lane butterfly, then cross-wave via tiny LDS array
#pragma unroll
    for (int off = 1; off < 16; off <<= 1) {
#pragma unroll
        for (int r = 0; r < 4; ++r) part[r] += __shfl_xor(part[r], off);
    }
    if (ln == 0) {
#pragma unroll
        for (int r = 0; r < 4; ++r) wsum[wave][u * 4 + r] = part[r];
    }
    __syncthreads();
    if (tid < 16)
        invd[tid] = 1.0f / (wsum[0][tid] + wsum[1][tid] + wsum[2][tid] + wsum[3][tid]);
    __syncthreads();

    // A2 frag: A[m=g2][k=g] = Ww[g][g2] * invden[g], zero-padded
    bf16x8 a2;
    {
        u16 t[8];
#pragma unroll
        for (int j = 0; j < 8; ++j) {
            const int k = u * 8 + j;
            t[j] = (k < HH && ln < HH) ? f2bf(Ww[k * HH + ln] * invd[k]) : (u16)0;
        }
        __builtin_memcpy(&a2, t, 16);
    }
    f32x4 c2 = {0.f, 0.f, 0.f, 0.f};
#pragma unroll
    for (int r = 0; r < 4; ++r) {
        const int g = u * 4 + r;
        c2[r] = (g < HH) ? bw[g] : 0.f;
    }

    // ---- mix2: read P rows, MFMA, write output in place
#pragma unroll
    for (int mi = 0; mi < 16; ++mi) {
        const int pos = posbase + mi * 16 + ln;
        const bf16x8 bfrag = *(const bf16x8*)&buf[pos * ROWB + fragoff];
        const f32x4 d = __builtin_amdgcn_mfma_f32_16x16x32_bf16(a2, bfrag, c2, 0, 0, 0);
        if (u < 3) {
            uint2 p;
            p.x = pack2(d[0], d[1]); p.y = pack2(d[2], d[3]);
            *(uint2*)&buf[pos * ROWB + u * 4] = p;
        }
    }
    __syncthreads();

    // ---- stream-out: reverse register transpose -> 12 coalesced uint2 stores
    {
        u32 rw[4][6];
#pragma unroll
        for (int i = 0; i < 4; ++i) {
            const uint4 a = *(const uint4*)&buf[(kc + i) * ROWB + 0];
            const uint2 b = *(const uint2*)&buf[(kc + i) * ROWB + 8];
            rw[i][0] = a.x; rw[i][1] = a.y; rw[i][2] = a.z;
            rw[i][3] = a.w; rw[i][4] = b.x; rw[i][5] = b.y;
        }
#pragma unroll
        for (int g = 0; g < HH; ++g) {
            const u32 sel = (g & 1) ? 0x07060302u : 0x05040100u;
            uint2 p;
            p.x = __builtin_amdgcn_perm(rw[1][g >> 1], rw[0][g >> 1], sel);
            p.y = __builtin_amdgcn_perm(rw[3][g >> 1], rw[2][g >> 1], sel);
            *(uint2*)&attn2[gbase + (size_t)g * SS * SS] = p;
        }
    }
}

// ---------------- conversion kernels ----------------

__global__ __launch_bounds__(256) void cvt_bf16_kernel(
    const float* __restrict__ in, u16* __restrict__ out, int n8)
{
    const int i = blockIdx.x * 256 + threadIdx.x;
    if (i >= n8) return;
    const float4 a = ((const float4*)in)[i * 2];
    const float4 b = ((const float4*)in)[i * 2 + 1];
    uint4 p;
    p.x = pack2(a.x, a.y); p.y = pack2(a.z, a.w);
    p.z = pack2(b.x, b.y); p.w = pack2(b.z, b.w);
    ((uint4*)out)[i] = p;
}

__global__ __launch_bounds__(256) void cvt_transpose_kernel(
    const float* __restrict__ in, u16* __restrict__ out, int R, int C)
{
    __shared__ float t[32][33];
    const int c0 = blockIdx.x * 32, r0 = blockIdx.y * 32;
    const int tr = threadIdx.x >> 3;
    const int tc = (threadIdx.x & 7) * 4;
    const float4 v = *(const float4*)&in[(size_t)(r0 + tr) * C + c0 + tc];
    t[tc + 0][tr] = v.x; t[tc + 1][tr] = v.y;
    t[tc + 2][tr] = v.z; t[tc + 3][tr] = v.w;
    __syncthreads();
    uint2 p;
    p.x = pack2(t[tr][tc + 0], t[tr][tc + 1]);
    p.y = pack2(t[tr][tc + 2], t[tr][tc + 3]);
    *(uint2*)&out[(size_t)(c0 + tr) * R + r0 + tc] = p;
}

// ---------------- launch ----------------
extern "C" void kernel_launch(void* const* d_in, const int* in_sizes, int n_in,
                              void* d_out, int out_size, void* d_ws, size_t ws_size,
                              hipStream_t stream)
{
    const float* x     = (const float*)d_in[0];
    const float* Wqkv  = (const float*)d_in[1];
    const float* bqkv  = (const float*)d_in[2];
    const float* Wl    = (const float*)d_in[3];
    const float* bl    = (const float*)d_in[4];
    const float* Ww    = (const float*)d_in[5];
    const float* bw    = (const float*)d_in[6];
    const float* Wproj = (const float*)d_in[7];
    const float* bproj = (const float*)d_in[8];
    float* out = (float*)d_out;

    // workspace (bf16 elems)
    const size_t N_XB  = (size_t)BB * SS * DD;
    const size_t N_QB  = (size_t)BB * HH * SS * DH;
    const size_t N_WT  = (size_t)DD * 3 * DD;
    const size_t N_WP  = (size_t)DD * DD;
    const size_t N_AT1 = (size_t)HH * SS * SS;

    u16* xb  = (u16*)d_ws;
    u16* qb  = xb  + N_XB;
    u16* kb  = qb  + N_QB;
    u16* vb  = kb  + N_QB;
    u16* vt  = vb  + N_QB;
    u16* ctx = vt  + N_QB;
    u16* Wqkv_t = ctx + N_XB;
    u16* Wproj_t = Wqkv_t + N_WT;
    u16* attn = Wproj_t + N_WP;

    const size_t fixed_bytes = (size_t)(N_XB * 2 + N_QB * 4 + N_WT + N_WP) * 2;
    int b_per = BB;
    while (b_per > 1 &&
           fixed_bytes + (size_t)b_per * N_AT1 * 2 * 2 > ws_size)
        b_per >>= 1;
    const int n_iter = BB / b_per;
    u16* attn2 = attn + (size_t)b_per * N_AT1;

    const dim3 blk(256);

    // 0) conversions
    cvt_bf16_kernel<<<dim3((N_XB / 8 + 255) / 256), blk, 0, stream>>>(x, xb, (int)(N_XB / 8));
    cvt_transpose_kernel<<<dim3(3 * DD / 32, DD / 32), blk, 0, stream>>>(Wqkv, Wqkv_t, DD, 3 * DD);
    cvt_transpose_kernel<<<dim3(DD / 32, DD / 32), blk, 0, stream>>>(Wproj, Wproj_t, DD, DD);

    // 1) QKV projection (qb scaled, kb, vb) + v transpose
    qkv_gemm_kernel<<<dim3(3 * DD / 128, BB * SS / 128), blk, 0, stream>>>(
        xb, Wqkv_t, bqkv, qb, kb, vb);
    vtrans_kernel<<<dim3(SS / 64, BB * HH), blk, 0, stream>>>(vb, vt);

    for (int it = 0; it < n_iter; ++it) {
        const int bh0 = it * b_per * HH;
        // 2) logits
        qk_gemm_kernel<<<dim3(SS / 128, SS / 128, b_per * HH), blk, 0, stream>>>(
            qb, kb, attn, bh0);
        // 3) mix1 + softmax + mix2 (MFMA, [pos][h] layout)
        mix_softmax_kernel<<<dim3(b_per * SS), blk, 0, stream>>>(
            attn, attn2, Wl, bl, Ww, bw);
        // 4) PV (64x64 tiles)
        pv_gemm_kernel<<<dim3(1, SS / 64, b_per * HH), blk, 0, stream>>>(
            attn2, vt, ctx, bh0);
    }

    // 5) output projection
    proj_gemm_kernel<<<dim3(DD / 64, BB * SS / 128), blk, 0, stream>>>(
        ctx, Wproj_t, bproj, out);
}